// Round 2
// baseline (72.876 us; speedup 1.0000x reference)
//
#include <hip/hip_runtime.h>
#include <math.h>

#define DIM 256

// ---------------------------------------------------------------------------
// Setup kernel: 1 block, 256 threads. Builds the Pauli-transfer coefficients
// T[q][p] (q=0..3 output qubit, p = p0*64+p1*16+p2*4+p3, pauli 0=I,1=X,2=Y,3=Z)
// such that  z_q = sum_p T[q][p] * prod_i a_i[p_i]
// where a_i is qubit i's Bloch vector (a_i[0]=1) AFTER encoding+layer0 gates
// but WITHOUT any depolarize shrink (folded into T).
//
// Method: numerically accumulate V = (RZ3 RY3 C30)(RZ2 RY2 C23)(RZ1 RY1 C12)
// (RZ0 RY0 C01) as a 16x16 complex matrix in LDS, then O_q = V^dag Z_q V,
// then t = Re Tr(P O_q)/16 * s^(1+nnz(P)),  s = 1 - 4*0.05/3.
// Qubit q <-> index bit (3-q)  (qubit 0 = MSB, matching the reference).
// ---------------------------------------------------------------------------
__global__ void qc_setup_kernel(const float* __restrict__ qw, float* __restrict__ T)
{
  __shared__ float Vr[16][16], Vi[16][16];
  __shared__ float Or[16][16], Oi[16][16];
  const int tid = threadIdx.x;
  const int r = tid >> 4, c = tid & 15;

  Vr[r][c] = (r == c) ? 1.0f : 0.0f;
  Vi[r][c] = 0.0f;
  __syncthreads();

  #pragma unroll 1
  for (int i = 0; i < 4; ++i) {
    const int cm = 8 >> i;             // control mask (qubit i)
    const int tm = 8 >> ((i + 1) & 3); // target mask (qubit (i+1)%4)
    // --- CNOT(control=i, target=(i+1)%4):  V <- G V,  G is a permutation
    {
      const int k = (r & cm) ? (r ^ tm) : r;
      const float nr = Vr[k][c], ni = Vi[k][c];
      __syncthreads();
      Vr[r][c] = nr; Vi[r][c] = ni;
      __syncthreads();
    }
    const float w  = qw[4 + i];        // qweights[1][i]
    const float ch = cosf(0.5f * w), sh = sinf(0.5f * w);
    // --- RY(w) on qubit i: u = [[ch,-sh],[sh,ch]]
    {
      const int m = 8 >> i;
      const int r0 = r & ~m, r1 = r | m;
      float u0, u1;
      if (r & m) { u0 = sh; u1 = ch; } else { u0 = ch; u1 = -sh; }
      const float nr = u0 * Vr[r0][c] + u1 * Vr[r1][c];
      const float ni = u0 * Vi[r0][c] + u1 * Vi[r1][c];
      __syncthreads();
      Vr[r][c] = nr; Vi[r][c] = ni;
      __syncthreads();
    }
    // --- RZ(w) on qubit i: diag(e^{-iw/2}, e^{+iw/2}) — own-element only
    {
      const int m = 8 >> i;
      const float pr = ch;
      const float pi = (r & m) ? sh : -sh;
      const float vr = Vr[r][c], vi = Vi[r][c];
      Vr[r][c] = pr * vr - pi * vi;
      Vi[r][c] = pr * vi + pi * vr;
      __syncthreads();
    }
  }

  const float sdep = 1.0f - 4.0f * 0.05f / 3.0f;
  const int p0 = tid >> 6, p1 = (tid >> 4) & 3, p2 = (tid >> 2) & 3, p3 = tid & 3;

  #pragma unroll 1
  for (int q = 0; q < 4; ++q) {
    const int zm = 8 >> q;
    // O[r][c] = sum_k conj(V[k][r]) * sign_q(k) * V[k][c]
    float orr = 0.0f, oii = 0.0f;
    for (int k = 0; k < 16; ++k) {
      const float sgn = (k & zm) ? -1.0f : 1.0f;
      const float ar = Vr[k][r], ai = -Vi[k][r];
      const float br = Vr[k][c], bi = Vi[k][c];
      orr += sgn * (ar * br - ai * bi);
      oii += sgn * (ar * bi + ai * br);
    }
    __syncthreads();
    Or[r][c] = orr; Oi[r][c] = oii;
    __syncthreads();

    // thread tid <-> Pauli string p;  Tr(P O) = sum_n P[n][m(n)] * O[m(n)][n]
    float tr = 0.0f;
    for (int n = 0; n < 16; ++n) {
      int m = n;
      float fr = 1.0f, fi = 0.0f;
      #pragma unroll
      for (int i2 = 0; i2 < 4; ++i2) {
        const int a   = (n >> (3 - i2)) & 1;
        const int pi_ = (i2 == 0) ? p0 : (i2 == 1) ? p1 : (i2 == 2) ? p2 : p3;
        if (pi_ == 1) {                    // X: flip, value 1
          m ^= (8 >> i2);
        } else if (pi_ == 2) {             // Y: flip, value (a? +i : -i)
          m ^= (8 >> i2);
          const float s2  = a ? 1.0f : -1.0f;
          const float nfr = -fi * s2, nfi = fr * s2;
          fr = nfr; fi = nfi;
        } else if (pi_ == 3) {             // Z: value (a? -1 : +1)
          if (a) { fr = -fr; fi = -fi; }
        }
      }
      tr += fr * Or[m][n] - fi * Oi[m][n];
    }
    const int nnz = (p0 != 0) + (p1 != 0) + (p2 != 0) + (p3 != 0);
    float scale = 1.0f / 16.0f;
    for (int e = 0; e <= nnz; ++e) scale *= sdep;   // sdep^(1+nnz) / 16
    T[q * 256 + tid] = tr * scale;
    __syncthreads();   // Or/Oi reused next q
  }
}

// ---------------------------------------------------------------------------
// Fused main kernel: one wave (64 lanes) per batch row, grid-stride.
// lane covers columns 4*lane .. 4*lane+3 of the row for both GEMV phases.
// ---------------------------------------------------------------------------
__device__ __forceinline__ float sel3(int p, float vx, float vy, float vz)
{
  float r = 1.0f;
  r = (p == 1) ? vx : r;
  r = (p == 2) ? vy : r;
  r = (p == 3) ? vz : r;
  return r;
}

__global__ __launch_bounds__(256) void qlayer_fused_kernel(
    const float* __restrict__ x,
    const float* __restrict__ Win,
    const float* __restrict__ b_in,
    const float* __restrict__ gamma,
    const float* __restrict__ beta,
    const float* __restrict__ qw,
    const float* __restrict__ Wout,
    const float* __restrict__ b_out,
    const float* __restrict__ T,
    float* __restrict__ out,
    int B)
{
  const int lane = threadIdx.x & 63;
  const int wid  = blockIdx.x * (blockDim.x >> 6) + (threadIdx.x >> 6);
  const int nw   = gridDim.x * (blockDim.x >> 6);

  // ---- hoisted per-lane fragments (constant across rows) ----
  float4 winf[4], tf[4];
  #pragma unroll
  for (int q = 0; q < 4; ++q) {
    winf[q] = *reinterpret_cast<const float4*>(&Win[q * 256 + lane * 4]);
    tf[q]   = *reinterpret_cast<const float4*>(&T[q * 256 + lane * 4]);
  }
  float4 woutf[4];
  #pragma unroll
  for (int j = 0; j < 4; ++j)
    woutf[j] = *reinterpret_cast<const float4*>(&Wout[(lane * 4 + j) * 4]);
  const float4 boutf = *reinterpret_cast<const float4*>(&b_out[lane * 4]);

  float bi[4], ga[4], be[4], cw0[4], sw0[4], cw1[4], sw1[4];
  #pragma unroll
  for (int i = 0; i < 4; ++i) {
    bi[i] = b_in[i]; ga[i] = gamma[i]; be[i] = beta[i];
    const float w0 = qw[i], w1 = qw[4 + i];
    cw0[i] = cosf(w0); sw0[i] = sinf(w0);
    cw1[i] = cosf(w1); sw1[i] = sinf(w1);
  }

  // per-lane Pauli indices: string p = 4*lane + j  (j = p3)
  const int p0 = lane >> 4, p1 = (lane >> 2) & 3, p2 = lane & 3;

  for (int row = wid; row < B; row += nw) {
    const size_t base = (size_t)row * DIM + lane * 4;
    const float4 xv = *reinterpret_cast<const float4*>(&x[base]);

    // ---- angles GEMV: acc[q] = sum_d x[row][d] * Win[q][d] ----
    float acc[4];
    #pragma unroll
    for (int q = 0; q < 4; ++q)
      acc[q] = xv.x * winf[q].x + xv.y * winf[q].y + xv.z * winf[q].z + xv.w * winf[q].w;
    #pragma unroll
    for (int off = 32; off > 0; off >>= 1) {
      #pragma unroll
      for (int q = 0; q < 4; ++q) acc[q] += __shfl_xor(acc[q], off, 64);
    }

    // ---- tanh + LayerNorm(4) ----
    float xp[4];
    #pragma unroll
    for (int q = 0; q < 4; ++q) {
      const float e = __expf(2.0f * (acc[q] + bi[q]));
      xp[q] = 1.0f - __fdividef(2.0f, e + 1.0f);   // tanh, inf-safe
    }
    const float mu = 0.25f * (xp[0] + xp[1] + xp[2] + xp[3]);
    const float d0 = xp[0] - mu, d1 = xp[1] - mu, d2 = xp[2] - mu, d3 = xp[3] - mu;
    const float var = 0.25f * (d0 * d0 + d1 * d1 + d2 * d2 + d3 * d3);
    const float inv = rsqrtf(var + 1e-5f);

    // ---- Bloch vector per qubit after RX(t)RZ(t)RX(w0)RZ(w1) ----
    float Ax[4], Ay[4], Az[4];
    #pragma unroll
    for (int i = 0; i < 4; ++i) {
      const float ang = ((i == 0 ? d0 : i == 1 ? d1 : i == 2 ? d2 : d3) * inv) * ga[i] + be[i];
      float sn, cs;
      __sincosf(ang, &sn, &cs);
      const float ax = sn * sn;       // after RX(t): (0,-s,c); RZ(t): (s^2,-sc,c)
      const float ay = -sn * cs;
      const float az = cs;
      const float ay2 = ay * cw0[i] - az * sw0[i];   // RX(w0)
      const float az2 = ay * sw0[i] + az * cw0[i];
      const float ax3 = ax * cw1[i] - ay2 * sw1[i];  // RZ(w1)
      const float ay3 = ax * sw1[i] + ay2 * cw1[i];
      Ax[i] = ax3; Ay[i] = ay3; Az[i] = az2;
    }

    // ---- Pauli contraction: 4 strings per lane (p = 4*lane + j) ----
    const float base3 = sel3(p0, Ax[0], Ay[0], Az[0]) *
                        sel3(p1, Ax[1], Ay[1], Az[1]) *
                        sel3(p2, Ax[2], Ay[2], Az[2]);
    const float pr0 = base3;               // p3 = I
    const float pr1 = base3 * Ax[3];
    const float pr2 = base3 * Ay[3];
    const float pr3 = base3 * Az[3];

    float z[4];
    #pragma unroll
    for (int q = 0; q < 4; ++q)
      z[q] = tf[q].x * pr0 + tf[q].y * pr1 + tf[q].z * pr2 + tf[q].w * pr3;
    #pragma unroll
    for (int off = 32; off > 0; off >>= 1) {
      #pragma unroll
      for (int q = 0; q < 4; ++q) z[q] += __shfl_xor(z[q], off, 64);
    }

    // ---- epilogue: out = x + z @ Wout^T + b_out ----
    float4 o;
    o.x = xv.x + boutf.x + z[0] * woutf[0].x + z[1] * woutf[0].y + z[2] * woutf[0].z + z[3] * woutf[0].w;
    o.y = xv.y + boutf.y + z[0] * woutf[1].x + z[1] * woutf[1].y + z[2] * woutf[1].z + z[3] * woutf[1].w;
    o.z = xv.z + boutf.z + z[0] * woutf[2].x + z[1] * woutf[2].y + z[2] * woutf[2].z + z[3] * woutf[2].w;
    o.w = xv.w + boutf.w + z[0] * woutf[3].x + z[1] * woutf[3].y + z[2] * woutf[3].z + z[3] * woutf[3].w;
    *reinterpret_cast<float4*>(&out[base]) = o;
  }
}

extern "C" void kernel_launch(void* const* d_in, const int* in_sizes, int n_in,
                              void* d_out, int out_size, void* d_ws, size_t ws_size,
                              hipStream_t stream)
{
  const float* x     = (const float*)d_in[0];
  const float* Win   = (const float*)d_in[1];
  const float* b_in  = (const float*)d_in[2];
  const float* gamma = (const float*)d_in[3];
  const float* beta  = (const float*)d_in[4];
  const float* qw    = (const float*)d_in[5];
  const float* Wout  = (const float*)d_in[6];
  const float* b_out = (const float*)d_in[7];
  float* out = (float*)d_out;
  float* T   = (float*)d_ws;            // 4*256 floats = 4 KB
  const int B = in_sizes[0] / DIM;

  hipLaunchKernelGGL(qc_setup_kernel, dim3(1), dim3(256), 0, stream, qw, T);
  hipLaunchKernelGGL(qlayer_fused_kernel, dim3(2048), dim3(256), 0, stream,
                     x, Win, b_in, gamma, beta, qw, Wout, b_out, T, out, B);
}